// Round 1
// baseline (768.103 us; speedup 1.0000x reference)
//
#include <hip/hip_runtime.h>

// ---------------------------------------------------------------------------
// Decoder: fused cvt -> fused h0/c0 init GEMM -> gx GEMM -> 32 per-step
// launches that carry BOTH the LSTM step (256 blocks) AND the FC chunk for
// the h produced by the previous launch (79 piggyback blocks on idle CUs),
// -> one small FC tail chunk for h_32.
// Round-4 theory: the 89.5us FC GEMM dispatch rides the latency-bound step
// chain for free; mfma_gemm128 gains 2-phase LDS double-buffer (1 barrier/
// K-iter, load-compute overlap) + bijective XCD swizzle.
// ---------------------------------------------------------------------------

#define B_  64
#define T_  32
#define E_  512
#define H_  1024
#define V_  10000
#define F_  2048
#define FCB 79   // ceil(V_/128): FC column tiles

typedef short short8 __attribute__((ext_vector_type(8)));
typedef float floatx4 __attribute__((ext_vector_type(4)));

__device__ __forceinline__ float bf2f(unsigned short u) {
  union { unsigned int i; float f; } c; c.i = ((unsigned int)u) << 16; return c.f;
}
__device__ __forceinline__ unsigned short f2bf(float f) {
  union { float f; unsigned int i; } c; c.f = f;
  unsigned int x = c.i;
  return (unsigned short)((x + 0x7fffu + ((x >> 16) & 1u)) >> 16);
}
__device__ __forceinline__ float sigmoidf_(float x) {
  return 1.0f / (1.0f + __expf(-x));
}
// async global->LDS, 16B per lane. LDS dest must be linear in lane (16B/lane).
__device__ __forceinline__ void gl_lds16(const unsigned short* g, unsigned short* l) {
  __builtin_amdgcn_global_load_lds(
      (const __attribute__((address_space(1))) unsigned int*)g,
      (__attribute__((address_space(3))) unsigned int*)l, 16, 0, 0);
}
// bijective XCD-chunked block remap (m204 formula; identity when nwg < 8)
__device__ __forceinline__ int xcd_swz(int lin, int nwg) {
  if (nwg < 8) return lin;
  int q = nwg >> 3, r = nwg & 7;
  int xcd = lin & 7, pos = lin >> 3;
  return (xcd < r ? xcd * (q + 1) : r * (q + 1) + (xcd - r) * q) + pos;
}

// ---------------- fused fp32 -> bf16 convert for all 6 arrays --------------
#define C_WIH  524288    // 4H*E/4
#define C_WHH  1048576   // 4H*H/4
#define C_WFC  2560000   // V*H/4
#define C_WI0  524288    // H*F/4
#define C_WC0  524288
#define C_FEA  32768     // B*F/4
#define C_TOT  (C_WIH + C_WHH + C_WFC + C_WI0 + C_WC0 + C_FEA)

__global__ __launch_bounds__(256) void cvt_all(
    const float* __restrict__ s0, const float* __restrict__ s1,
    const float* __restrict__ s2, const float* __restrict__ s3,
    const float* __restrict__ s4, const float* __restrict__ s5,
    unsigned short* __restrict__ d0, unsigned short* __restrict__ d1,
    unsigned short* __restrict__ d2, unsigned short* __restrict__ d3,
    unsigned short* __restrict__ d4, unsigned short* __restrict__ d5) {
  int i = blockIdx.x * blockDim.x + threadIdx.x;
  int stride = gridDim.x * blockDim.x;
  for (; i < C_TOT; i += stride) {
    const float* s; unsigned short* d; int j = i;
    if (j < C_WIH)            { s = s0; d = d0; }
    else if ((j -= C_WIH) < C_WHH) { s = s1; d = d1; }
    else if ((j -= C_WHH) < C_WFC) { s = s2; d = d2; }
    else if ((j -= C_WFC) < C_WI0) { s = s3; d = d3; }
    else if ((j -= C_WI0) < C_WC0) { s = s4; d = d4; }
    else { j -= C_WC0; s = s5; d = d5; }
    float4 v = ((const float4*)s)[j];
    ushort4 o;
    o.x = f2bf(v.x); o.y = f2bf(v.y); o.z = f2bf(v.z); o.w = f2bf(v.w);
    ((ushort4*)d)[j] = o;
  }
}

// ---------------- embedding gather -> bf16, rows ordered (t*64+b) ----------
__global__ __launch_bounds__(128) void embed_gather(
    const float* __restrict__ table, const int* __restrict__ captions,
    unsigned short* __restrict__ out) {
  int row = blockIdx.x;            // row = t*B + b
  int t = row >> 6, b = row & 63;
  int idx = captions[b * T_ + t];
  const float4* src = (const float4*)(table + (size_t)idx * E_);
  ushort4* dst = (ushort4*)(out + (size_t)row * E_);
  for (int e = threadIdx.x; e < E_ / 4; e += blockDim.x) {
    float4 v = src[e];
    ushort4 o;
    o.x = f2bf(v.x); o.y = f2bf(v.y); o.z = f2bf(v.z); o.w = f2bf(v.w);
    dst[e] = o;
  }
}

// ---------------- 128x128 LDS-staged bf16 MFMA GEMM ------------------------
// C = act(A @ W^T + bias).  2-phase double-buffer: stage(next) issued before
// compute(cur); single barrier per K-iter (syncthreads drains vmcnt).
// XOR bank swizzle: LDS row of 32 shorts, 16B slot s holds global chunk
// s^(row&3) (global side permuted; LDS stays lane-linear for gl_lds).
// OUT_INIT: N=2048 fused h0|c0 -> out (bf16, stride H_) / out2 (f32).
template <int ACT_SIGMOID, int OUT_BF16, int OUT_INIT>
__global__ __launch_bounds__(256) void mfma_gemm128(
    const unsigned short* __restrict__ A, const unsigned short* __restrict__ W,
    const float* __restrict__ bias1, const float* __restrict__ bias2,
    void* __restrict__ out, void* __restrict__ out2, int M, int N, int K) {
  __shared__ unsigned short At[2][128 * 32];   // 16 KB
  __shared__ unsigned short Wt[2][128 * 32];   // 16 KB

  const int tid  = threadIdx.x;
  const int lane = tid & 63;
  const int wave = tid >> 6;
  const int l15  = lane & 15;
  const int quad = lane >> 4;
  const int wm   = (wave >> 1) * 64;
  const int wn   = (wave & 1) * 64;

  const int gx  = gridDim.x;
  const int nwg = gx * gridDim.y;
  const int wg  = xcd_swz(blockIdx.y * gx + blockIdx.x, nwg);
  const int m0  = (wg % gx) * 128;
  const int n0  = (wg / gx) * 128;
  const int ksl = (quad ^ (l15 & 3)) * 8;  // swizzled k-chunk for frag reads

  const int c0i = tid, c1i = tid + 256;
  const int ar0 = c0i >> 2, ak0 = (((c0i & 3) ^ (ar0 & 3)) * 8);
  const int ar1 = c1i >> 2, ak1 = (((c1i & 3) ^ (ar1 & 3)) * 8);
  int am0 = m0 + ar0; if (am0 > M - 1) am0 = M - 1;
  int am1 = m0 + ar1; if (am1 > M - 1) am1 = M - 1;
  int wn0 = n0 + ar0; if (wn0 > N - 1) wn0 = N - 1;
  int wn1 = n0 + ar1; if (wn1 > N - 1) wn1 = N - 1;
  const unsigned short* Ag0 = A + (size_t)am0 * K + ak0;
  const unsigned short* Ag1 = A + (size_t)am1 * K + ak1;
  const unsigned short* Wg0 = W + (size_t)wn0 * K + ak0;
  const unsigned short* Wg1 = W + (size_t)wn1 * K + ak1;

  floatx4 acc[4][4];
#pragma unroll
  for (int i = 0; i < 4; ++i)
#pragma unroll
    for (int j = 0; j < 4; ++j) acc[i][j] = (floatx4){0.f, 0.f, 0.f, 0.f};

  // prologue stage of k-tile 0 into buffer 0
  gl_lds16(Ag0, &At[0][c0i * 8]);
  gl_lds16(Ag1, &At[0][c1i * 8]);
  gl_lds16(Wg0, &Wt[0][c0i * 8]);
  gl_lds16(Wg1, &Wt[0][c1i * 8]);
  __syncthreads();

  int cur = 0;
  for (int k0 = 0; k0 < K; k0 += 32) {
    const int kn = k0 + 32;
    if (kn < K) {                      // issue next tile before compute
      const int nb = cur ^ 1;
      gl_lds16(Ag0 + kn, &At[nb][c0i * 8]);
      gl_lds16(Ag1 + kn, &At[nb][c1i * 8]);
      gl_lds16(Wg0 + kn, &Wt[nb][c0i * 8]);
      gl_lds16(Wg1 + kn, &Wt[nb][c1i * 8]);
    }
    short8 a[4], b[4];
#pragma unroll
    for (int mt = 0; mt < 4; ++mt)
      a[mt] = *(const short8*)&At[cur][(wm + mt * 16 + l15) * 32 + ksl];
#pragma unroll
    for (int nt = 0; nt < 4; ++nt)
      b[nt] = *(const short8*)&Wt[cur][(wn + nt * 16 + l15) * 32 + ksl];
#pragma unroll
    for (int mt = 0; mt < 4; ++mt)
#pragma unroll
      for (int nt = 0; nt < 4; ++nt)
        acc[mt][nt] = __builtin_amdgcn_mfma_f32_16x16x32_bf16(a[mt], b[nt], acc[mt][nt], 0, 0, 0);
    __syncthreads();                   // drains vmcnt: next tile resident
    cur ^= 1;
  }

#pragma unroll
  for (int nt = 0; nt < 4; ++nt) {
    int col = n0 + wn + nt * 16 + l15;
    if (col >= N) continue;
    float bsum;
    if (OUT_INIT)
      bsum = (col < H_) ? bias1[col] : bias2[col - H_];
    else
      bsum = (bias1 ? bias1[col] : 0.f) + (bias2 ? bias2[col] : 0.f);
#pragma unroll
    for (int mt = 0; mt < 4; ++mt) {
#pragma unroll
      for (int r = 0; r < 4; ++r) {
        int m = m0 + wm + mt * 16 + quad * 4 + r;
        if (m >= M) continue;
        float v = acc[mt][nt][r] + bsum;
        if (ACT_SIGMOID) v = sigmoidf_(v);
        if (OUT_INIT) {
          if (col < H_)
            ((unsigned short*)out)[(size_t)m * H_ + col] = f2bf(v);
          else
            ((float*)out2)[(size_t)m * H_ + (col - H_)] = v;
        } else if (OUT_BF16) {
          ((unsigned short*)out)[(size_t)m * N + col] = f2bf(v);
        } else {
          ((float*)out)[(size_t)m * N + col] = v;
        }
      }
    }
  }
}

// ---------------- fused per-step LSTM + piggyback FC chunk -----------------
// Blocks [0, fc_base): LSTM step for h_{t+1} (unchanged round-3 structure).
// Blocks [fc_base, ...): FC chunk out = sigmoid(h_t @ W_fc^T + b_fc) for the
// h produced by the PREVIOUS launch -- rides the latency-bound step chain on
// idle CUs. FC role: 8-wave 64x128 tile, BK=64 (16 iters), 2-phase dbuf,
// XOR slot swizzle over 8 slots (slot ^ (row&7)).
#define WSPAD 1032   // 1024 + 8 bf16 pad per row (stride 516 dwords: 2-way)
#define SMEM_BYTES 49152   // max(step 41728, fc 49152)
__global__ __launch_bounds__(512, 2) void lstm_step_fc(
    const unsigned short* __restrict__ W_hh_b,  // [4H,H] bf16
    const unsigned short* __restrict__ gx_t,    // [B,4H] bf16 (x-part+biases)
    float* __restrict__ c,                      // [B,H] f32, in-place
    const unsigned short* __restrict__ h_in,    // [B,H] bf16 (= h_t)
    unsigned short* __restrict__ h_out,         // [B,H] bf16 (= h_{t+1})
    const unsigned short* __restrict__ W_fc_b,  // [V,H] bf16
    const float* __restrict__ b_fc,             // [V] f32
    float* __restrict__ fc_out,                 // out rows for h_t, or null
    int fc_base) {
  __shared__ __align__(16) char smem[SMEM_BYTES];

  const int tid  = threadIdx.x;
  const int lane = tid & 63;
  const int wave = tid >> 6;        // 0..7
  const int l15  = lane & 15;
  const int quad = lane >> 4;

  if ((int)blockIdx.x >= fc_base) {
    // ------------------------- FC role -------------------------
    if (!fc_out) return;
    unsigned short* Ah = (unsigned short*)smem;             // [2][64*64]
    unsigned short* Wf = (unsigned short*)(smem + 16384);   // [2][128*64]
    const int n0 = ((int)blockIdx.x - fc_base) * 128;
    // fragment-read swizzled slots (two K=32 sub-steps of the BK=64 tile)
    const int ksl0 = ((quad    ) ^ (l15 & 7)) * 8;
    const int ksl1 = ((quad + 4) ^ (l15 & 7)) * 8;
    // staging: A 512 chunks (row=tid>>3 of 64, slot=tid&7); W 1024 chunks
    // (rows tid>>3 and 64+(tid>>3)); global k-chunk = (slot ^ (row&7)).
    const int arow  = tid >> 3;          // 0..63
    const int aslot = tid & 7;
    const int agk   = ((aslot ^ (arow & 7)) * 8);
    int wr0 = n0 + arow;       if (wr0 > V_ - 1) wr0 = V_ - 1;
    int wr1 = n0 + 64 + arow;  if (wr1 > V_ - 1) wr1 = V_ - 1;
    const unsigned short* Ag  = h_in   + (size_t)arow * H_ + agk;
    const unsigned short* Wg0 = W_fc_b + (size_t)wr0 * H_ + agk;
    const unsigned short* Wg1 = W_fc_b + (size_t)wr1 * H_ + agk;

    floatx4 acc[4];
#pragma unroll
    for (int mt = 0; mt < 4; ++mt) acc[mt] = (floatx4){0.f, 0.f, 0.f, 0.f};

    gl_lds16(Ag,  &Ah[tid * 8]);
    gl_lds16(Wg0, &Wf[tid * 8]);
    gl_lds16(Wg1, &Wf[4096 + tid * 8]);
    __syncthreads();

    int cur = 0;
    for (int k0 = 0; k0 < H_; k0 += 64) {
      const int kn = k0 + 64;
      if (kn < H_) {
        const int nb = cur ^ 1;
        gl_lds16(Ag  + kn, &Ah[nb * 4096 + tid * 8]);
        gl_lds16(Wg0 + kn, &Wf[nb * 8192 + tid * 8]);
        gl_lds16(Wg1 + kn, &Wf[nb * 8192 + 4096 + tid * 8]);
      }
      short8 a0[4], a1[4];
#pragma unroll
      for (int mt = 0; mt < 4; ++mt) {
        a0[mt] = *(const short8*)&Ah[cur * 4096 + (mt * 16 + l15) * 64 + ksl0];
        a1[mt] = *(const short8*)&Ah[cur * 4096 + (mt * 16 + l15) * 64 + ksl1];
      }
      short8 b0 = *(const short8*)&Wf[cur * 8192 + (wave * 16 + l15) * 64 + ksl0];
      short8 b1 = *(const short8*)&Wf[cur * 8192 + (wave * 16 + l15) * 64 + ksl1];
#pragma unroll
      for (int mt = 0; mt < 4; ++mt)
        acc[mt] = __builtin_amdgcn_mfma_f32_16x16x32_bf16(a0[mt], b0, acc[mt], 0, 0, 0);
#pragma unroll
      for (int mt = 0; mt < 4; ++mt)
        acc[mt] = __builtin_amdgcn_mfma_f32_16x16x32_bf16(a1[mt], b1, acc[mt], 0, 0, 0);
      __syncthreads();
      cur ^= 1;
    }

    const int col = n0 + wave * 16 + l15;
    if (col < V_) {
      const float bs = b_fc[col];
#pragma unroll
      for (int mt = 0; mt < 4; ++mt) {
#pragma unroll
        for (int r = 0; r < 4; ++r) {
          int m = mt * 16 + quad * 4 + r;     // 0..63
          fc_out[(size_t)m * V_ + col] = sigmoidf_(acc[mt][r] + bs);
        }
      }
    }
    return;
  }

  // ------------------------- step role (round-3 structure) -----------------
  unsigned short* Ws = (unsigned short*)smem;                       // 16*WSPAD
  float (*gbuf)[B_][17] = (float (*)[B_][17])(smem + 16 * WSPAD * 2);

  const int kb   = quad * 8;
  const int kh   = wave >> 2;       // K half: [kh*512, kh*512+512)
  const int mt   = wave & 3;        // batch tile: batches mt*16..+15
  const int colbase = blockIdx.x * 4;

  // ---- async-stage 16 W_hh rows into LDS (gate-major) ----
#pragma unroll
  for (int it = 0; it < 4; ++it) {
    int row  = it * 4 + (wave >> 1);
    int half = wave & 1;
    int grow = (row >> 2) * H_ + colbase + (row & 3);
    gl_lds16(W_hh_b + (size_t)grow * H_ + half * 512 + lane * 8,
             &Ws[row * WSPAD + half * 512]);
  }

  // ---- prefetch h fragment (16 x 16B) into registers (overlaps staging) ---
  const unsigned short* hp = h_in + (size_t)(mt * 16 + l15) * H_ + kh * 512 + kb;
  short8 hx[16];
#pragma unroll
  for (int i = 0; i < 16; ++i)
    hx[i] = *(const short8*)(hp + i * 32);

  // ---- prefetch cell inputs (waves 0-3 only; wave-uniform branch) ---------
  const int cb = tid >> 2, cj = tid & 3;
  float gxi = 0.f, gxf = 0.f, gxg = 0.f, gxo = 0.f, c_old = 0.f;
  if (tid < 256) {
    const unsigned short* gxp = gx_t + (size_t)cb * (4 * H_) + colbase + cj;
    gxi = bf2f(gxp[0 * H_]);
    gxf = bf2f(gxp[1 * H_]);
    gxg = bf2f(gxp[2 * H_]);
    gxo = bf2f(gxp[3 * H_]);
    c_old = c[cb * H_ + colbase + cj];
  }

  __syncthreads();   // drains vmcnt: staging + prefetches complete

  floatx4 a0 = (floatx4){0,0,0,0}, a1 = a0, a2 = a0, a3 = a0;
#pragma unroll
  for (int i = 0; i < 16; i += 4) {
    short8 w0 = *(const short8*)&Ws[l15 * WSPAD + kh * 512 + kb + (i + 0) * 32];
    short8 w1 = *(const short8*)&Ws[l15 * WSPAD + kh * 512 + kb + (i + 1) * 32];
    short8 w2 = *(const short8*)&Ws[l15 * WSPAD + kh * 512 + kb + (i + 2) * 32];
    short8 w3 = *(const short8*)&Ws[l15 * WSPAD + kh * 512 + kb + (i + 3) * 32];
    a0 = __builtin_amdgcn_mfma_f32_16x16x32_bf16(hx[i + 0], w0, a0, 0, 0, 0);
    a1 = __builtin_amdgcn_mfma_f32_16x16x32_bf16(hx[i + 1], w1, a1, 0, 0, 0);
    a2 = __builtin_amdgcn_mfma_f32_16x16x32_bf16(hx[i + 2], w2, a2, 0, 0, 0);
    a3 = __builtin_amdgcn_mfma_f32_16x16x32_bf16(hx[i + 3], w3, a3, 0, 0, 0);
  }
  floatx4 acc = (a0 + a1) + (a2 + a3);

#pragma unroll
  for (int r = 0; r < 4; ++r)
    gbuf[kh][mt * 16 + quad * 4 + r][l15] = acc[r];
  __syncthreads();

  // ---- cell math: thread owns (batch cb, col colbase+cj); waves 0-3 -------
  if (tid < 256) {
    float gi = gbuf[0][cb][0  + cj] + gbuf[1][cb][0  + cj] + gxi;
    float gf = gbuf[0][cb][4  + cj] + gbuf[1][cb][4  + cj] + gxf;
    float gg = gbuf[0][cb][8  + cj] + gbuf[1][cb][8  + cj] + gxg;
    float go = gbuf[0][cb][12 + cj] + gbuf[1][cb][12 + cj] + gxo;
    gi = sigmoidf_(gi);
    gf = sigmoidf_(gf);
    gg = tanhf(gg);
    go = sigmoidf_(go);
    int ci = cb * H_ + colbase + cj;
    float cn = gf * c_old + gi * gg;
    c[ci] = cn;
    h_out[ci] = f2bf(go * tanhf(cn));
  }
}

// ---------------------------------------------------------------------------
extern "C" void kernel_launch(void* const* d_in, const int* in_sizes, int n_in,
                              void* d_out, int out_size, void* d_ws, size_t ws_size,
                              hipStream_t stream) {
  const float* features    = (const float*)d_in[0];
  const int*   captions    = (const int*)d_in[1];
  const float* embed_table = (const float*)d_in[2];
  const float* W_init_h    = (const float*)d_in[3];
  const float* b_init_h    = (const float*)d_in[4];
  const float* W_init_c    = (const float*)d_in[5];
  const float* b_init_c    = (const float*)d_in[6];
  const float* W_ih        = (const float*)d_in[7];
  const float* b_ih        = (const float*)d_in[8];
  const float* W_hh        = (const float*)d_in[9];
  const float* b_hh        = (const float*)d_in[10];
  const float* W_fc        = (const float*)d_in[11];
  const float* b_fc        = (const float*)d_in[12];
  float* out = (float*)d_out;

  // ---- workspace carve-up (bump allocator, 256B aligned) ----
  char* ws = (char*)d_ws;
  auto alloc = [&](size_t bytes) -> char* {
    char* p = ws;
    ws += (bytes + 255) & ~(size_t)255;
    return p;
  };
  unsigned short* W_ih_b  = (unsigned short*)alloc((size_t)4 * H_ * E_ * 2);
  unsigned short* W_hh_b  = (unsigned short*)alloc((size_t)4 * H_ * H_ * 2);
  unsigned short* W_fc_b  = (unsigned short*)alloc((size_t)V_ * H_ * 2);
  // NOTE: Wih0_b and Wic0_b must stay CONTIGUOUS (fused [2H,F] init GEMM).
  unsigned short* Wih0_b  = (unsigned short*)alloc((size_t)H_ * F_ * 2);
  unsigned short* Wic0_b  = (unsigned short*)alloc((size_t)H_ * F_ * 2);
  unsigned short* feat_b  = (unsigned short*)alloc((size_t)B_ * F_ * 2);
  unsigned short* emb_b   = (unsigned short*)alloc((size_t)T_ * B_ * E_ * 2);
  unsigned short* gx_b    = (unsigned short*)alloc((size_t)T_ * B_ * 4 * H_ * 2);
  unsigned short* h_all   = (unsigned short*)alloc((size_t)(T_ + 1) * B_ * H_ * 2);
  float*          c_f32   = (float*)alloc((size_t)B_ * H_ * 4);
  (void)ws_size; (void)in_sizes; (void)n_in; (void)out_size; (void)Wic0_b;

  // ---- one fused fp32->bf16 conversion for all weights/features ----
  hipLaunchKernelGGL(cvt_all, dim3(4096), dim3(256), 0, stream,
                     W_ih, W_hh, W_fc, W_init_h, W_init_c, features,
                     W_ih_b, W_hh_b, W_fc_b, Wih0_b, Wic0_b, feat_b);

  hipLaunchKernelGGL(embed_gather, dim3(T_ * B_), dim3(128), 0, stream,
                     embed_table, captions, emb_b);

  // ---- fused h0|c0 init: one GEMM over N=2048 (Wih0_b||Wic0_b contiguous) -
  hipLaunchKernelGGL((mfma_gemm128<0, 1, 1>), dim3(1, 2 * H_ / 128), dim3(256), 0, stream,
                     feat_b, Wih0_b, b_init_h, b_init_c,
                     (void*)h_all, (void*)c_f32, B_, 2 * H_, F_);

  // ---- gx = emb @ W_ih^T + b_ih + b_hh for all t ----
  hipLaunchKernelGGL((mfma_gemm128<0, 1, 0>), dim3(T_ * B_ / 128, 4 * H_ / 128), dim3(256), 0, stream,
                     emb_b, W_ih_b, b_ih, b_hh, (void*)gx_b, (void*)nullptr,
                     T_ * B_, 4 * H_, E_);

  // ---- 32 sequential recurrent steps; launch t>=1 also carries the FC
  //      chunk for h_t (output time-row t-1) on 79 piggyback blocks --------
  for (int t = 0; t < T_; ++t) {
    int nblk = (t == 0) ? 256 : (256 + FCB);
    hipLaunchKernelGGL(lstm_step_fc, dim3(nblk), dim3(512), 0, stream,
                       W_hh_b,
                       gx_b + (size_t)t * B_ * 4 * H_,
                       c_f32,
                       h_all + (size_t)t * B_ * H_,
                       h_all + (size_t)(t + 1) * B_ * H_,
                       W_fc_b, b_fc,
                       (t == 0) ? (float*)nullptr : out + (size_t)(t - 1) * B_ * V_,
                       256);
  }

  // ---- FC tail chunk for h_32 (time-row 31): all-FC launch (fc_base=0) ----
  hipLaunchKernelGGL(lstm_step_fc, dim3(FCB), dim3(512), 0, stream,
                     W_hh_b, gx_b, c_f32,
                     h_all + (size_t)T_ * B_ * H_,   // FC input = h_32
                     h_all + (size_t)T_ * B_ * H_,   // unused
                     W_fc_b, b_fc,
                     out + (size_t)(T_ - 1) * B_ * V_,
                     0);
}